// Round 4
// baseline (452.483 us; speedup 1.0000x reference)
//
#include <hip/hip_runtime.h>
#include <hip/hip_bf16.h>
#include <cstdint>

// Problem constants: B=2, H=16, L=2048, D=64
#define L_SEQ 2048
#define D_HEAD 64
#define N_HEADS 16
#define NBH 32   // B*H

typedef __attribute__((ext_vector_type(8))) __bf16 bf16x8;
typedef __attribute__((ext_vector_type(4))) __bf16 bf16x4;
typedef __attribute__((ext_vector_type(4))) float f32x4;

// ============================ prep kernels ============================

// Qb = bf16(Q * scale * log2e)  (so epilogue is exp2);  Kb = bf16(K)
__global__ __launch_bounds__(256) void prep_qk(const float* __restrict__ Q,
                                               const float* __restrict__ K,
                                               const float* __restrict__ scale_p,
                                               __bf16* __restrict__ Qb,
                                               __bf16* __restrict__ Kb) {
    const float c = scale_p[0] * 1.4426950408889634f;
    const size_t i = ((size_t)blockIdx.x * 256 + threadIdx.x) * 4;
    float4 q = *(const float4*)(Q + i);
    float4 k = *(const float4*)(K + i);
    __bf16 qo[4], ko[4];
    qo[0] = (__bf16)(q.x * c); qo[1] = (__bf16)(q.y * c);
    qo[2] = (__bf16)(q.z * c); qo[3] = (__bf16)(q.w * c);
    ko[0] = (__bf16)k.x; ko[1] = (__bf16)k.y; ko[2] = (__bf16)k.z; ko[3] = (__bf16)k.w;
    *(bf16x4*)(Qb + i) = *(bf16x4*)qo;
    *(bf16x4*)(Kb + i) = *(bf16x4*)ko;
}

// VbT[bh][d][k] = bf16(V[bh][k][d])  -- tiled transpose through LDS
__global__ __launch_bounds__(256) void prep_vt(const float* __restrict__ V,
                                               __bf16* __restrict__ VbT) {
    __shared__ __bf16 tile[64][72];
    const int bh = blockIdx.x >> 5;
    const int kt = blockIdx.x & 31;
    const int tid = threadIdx.x;
    const int r = tid >> 2;          // 0..63
    const int c = (tid & 3) * 16;    // 0,16,32,48
    const float* src = V + ((size_t)bh * L_SEQ + (size_t)kt * 64 + r) * D_HEAD + c;
    #pragma unroll
    for (int i = 0; i < 4; ++i) {
        float4 f = ((const float4*)src)[i];
        tile[r][c + i * 4 + 0] = (__bf16)f.x;
        tile[r][c + i * 4 + 1] = (__bf16)f.y;
        tile[r][c + i * 4 + 2] = (__bf16)f.z;
        tile[r][c + i * 4 + 3] = (__bf16)f.w;
    }
    __syncthreads();
    __bf16 out[16];
    #pragma unroll
    for (int j = 0; j < 16; ++j) out[j] = tile[c + j][r];   // [k][d] -> row d
    __bf16* dst = VbT + ((size_t)bh * D_HEAD + r) * L_SEQ + (size_t)kt * 64 + c;
    *(bf16x8*)dst       = *(bf16x8*)&out[0];
    *(bf16x8*)(dst + 8) = *(bf16x8*)&out[8];
}

// pack mask int32 -> bit per k: mp[row][kword], row in [B*L), 64 words/row
__global__ __launch_bounds__(256) void prep_mask(const int* __restrict__ mask,
                                                 unsigned int* __restrict__ mp) {
    const int wv   = blockIdx.x * 4 + (threadIdx.x >> 6);
    const int lane = threadIdx.x & 63;
    const int row  = wv >> 5;            // 0..4095
    const int k0   = (wv & 31) * 64;
    const int m = mask[(size_t)row * L_SEQ + k0 + lane];
    const unsigned long long b = __ballot(m != 0);
    if (lane < 2) mp[row * 64 + (k0 >> 5) + lane] = (unsigned int)(b >> (32 * lane));
}

// ============================ main kernel ============================
// Swapped QK^T: per chunk of 64 k, wave computes S^T tiles D[k][q] via
// mfma(A=K, B=Q^T). Lane holds S^T[k=16t+4g+r][q=r15] -> mask bits and attn
// stores are contiguous-in-k per lane. No block barriers; only LDS use is a
// wave-private P bounce to build the PV A-fragment.
// Round-4 changes: plain (cached) attn/ctx stores so L2 merges 64B half-lines
// into full 128B dirty lines (kills the 1.47x write amplification seen with
// NT f32x4 stores); K fragments software-prefetched one chunk ahead.
__global__ __launch_bounds__(256, 4) void sdpa_main(
    const __bf16* __restrict__ Qb, const __bf16* __restrict__ Kb,
    const __bf16* __restrict__ VbT, const unsigned int* __restrict__ mp,
    float* __restrict__ ctx_out, float* __restrict__ attn_out)
{
    __shared__ __bf16 P_lds[4][16][72];

    const int tid = threadIdx.x;
    const int w   = tid >> 6;
    const int l   = tid & 63;
    const int r15 = l & 15;
    const int g   = l >> 4;

    // bijective XCD swizzle: 1024 blocks -> 128 consecutive per XCD
    const int bid = blockIdx.x;
    const int wg  = (bid & 7) * 128 + (bid >> 3);
    const int bh  = wg >> 5;
    const int qt  = wg & 31;
    const int b   = bh >> 4;

    const int qq = qt * 64 + w * 16 + r15;   // this lane's q row (QK/attn view)

    const __bf16* Qrow = Qb + ((size_t)bh * L_SEQ + qq) * D_HEAD;
    const bf16x8 qf0 = *(const bf16x8*)(Qrow + 8 * g);
    const bf16x8 qf1 = *(const bf16x8*)(Qrow + 32 + 8 * g);

    const __bf16* Kbase = Kb + (size_t)bh * L_SEQ * D_HEAD + (size_t)r15 * D_HEAD + 8 * g;
    const __bf16* Vbase = VbT + (size_t)bh * D_HEAD * L_SEQ + (size_t)r15 * L_SEQ + 8 * g;
    const unsigned int* mrow = mp + ((size_t)b * L_SEQ + qq) * 64;
    float* arow = attn_out + ((size_t)bh * L_SEQ + qq) * L_SEQ + 4 * g;

    // ---------------- pass 1: row sums ----------------
    float lsum = 0.f;
    {
        bf16x8 kf[8];
        #pragma unroll
        for (int t = 0; t < 4; ++t) {
            const __bf16* kp = Kbase + (size_t)(16 * t) * D_HEAD;
            kf[2 * t]     = *(const bf16x8*)kp;
            kf[2 * t + 1] = *(const bf16x8*)(kp + 32);
        }
        for (int ch = 0; ch < 32; ++ch) {
            const int k0 = ch * 64;
            // prefetch next chunk's K (safe re-load of current on last iter)
            const int k0n = (ch < 31) ? k0 + 64 : k0;
            bf16x8 kn[8];
            #pragma unroll
            for (int t = 0; t < 4; ++t) {
                const __bf16* kp = Kbase + (size_t)(k0n + 16 * t) * D_HEAD;
                kn[2 * t]     = *(const bf16x8*)kp;
                kn[2 * t + 1] = *(const bf16x8*)(kp + 32);
            }
            const uint2 mw = *(const uint2*)(mrow + ch * 2);
            f32x4 acc[4] = {{0,0,0,0},{0,0,0,0},{0,0,0,0},{0,0,0,0}};
            #pragma unroll
            for (int t = 0; t < 4; ++t) {
                acc[t] = __builtin_amdgcn_mfma_f32_16x16x32_bf16(kf[2*t],   qf0, acc[t], 0, 0, 0);
                acc[t] = __builtin_amdgcn_mfma_f32_16x16x32_bf16(kf[2*t+1], qf1, acc[t], 0, 0, 0);
            }
            #pragma unroll
            for (int t = 0; t < 4; ++t) {
                const unsigned int word = (t & 2) ? mw.y : mw.x;
                const unsigned int nib  = (word >> ((t & 1) * 16 + 4 * g)) & 0xFu;
                #pragma unroll
                for (int r = 0; r < 4; ++r) {
                    const float e = __builtin_exp2f(acc[t][r]);
                    lsum += ((nib >> r) & 1u) ? 0.f : e;
                }
            }
            #pragma unroll
            for (int i = 0; i < 8; ++i) kf[i] = kn[i];
        }
    }
    lsum += __shfl_xor(lsum, 16);
    lsum += __shfl_xor(lsum, 32);
    const float inv = 1.0f / lsum;

    // ---------------- pass 2: attn write + PV ----------------
    f32x4 ctx[4] = {{0,0,0,0},{0,0,0,0},{0,0,0,0},{0,0,0,0}};
    {
        bf16x8 kf[8];
        #pragma unroll
        for (int t = 0; t < 4; ++t) {
            const __bf16* kp = Kbase + (size_t)(16 * t) * D_HEAD;
            kf[2 * t]     = *(const bf16x8*)kp;
            kf[2 * t + 1] = *(const bf16x8*)(kp + 32);
        }
        for (int ch = 0; ch < 32; ++ch) {
            const int k0 = ch * 64;
            const int k0n = (ch < 31) ? k0 + 64 : k0;
            bf16x8 kn[8];
            #pragma unroll
            for (int t = 0; t < 4; ++t) {
                const __bf16* kp = Kbase + (size_t)(k0n + 16 * t) * D_HEAD;
                kn[2 * t]     = *(const bf16x8*)kp;
                kn[2 * t + 1] = *(const bf16x8*)(kp + 32);
            }
            const uint2 mw = *(const uint2*)(mrow + ch * 2);
            f32x4 acc[4] = {{0,0,0,0},{0,0,0,0},{0,0,0,0},{0,0,0,0}};
            #pragma unroll
            for (int t = 0; t < 4; ++t) {
                acc[t] = __builtin_amdgcn_mfma_f32_16x16x32_bf16(kf[2*t],   qf0, acc[t], 0, 0, 0);
                acc[t] = __builtin_amdgcn_mfma_f32_16x16x32_bf16(kf[2*t+1], qf1, acc[t], 0, 0, 0);
            }
            #pragma unroll
            for (int t = 0; t < 4; ++t) {
                const unsigned int word = (t & 2) ? mw.y : mw.x;
                const unsigned int nib  = (word >> ((t & 1) * 16 + 4 * g)) & 0xFu;
                f32x4 p;
                __bf16 pb[4];
                #pragma unroll
                for (int r = 0; r < 4; ++r) {
                    float e = __builtin_exp2f(acc[t][r]) * inv;
                    e = ((nib >> r) & 1u) ? 0.f : e;
                    p[r] = e;
                    pb[r] = (__bf16)e;
                }
                *(f32x4*)(arow + k0 + 16 * t) = p;   // plain store: L2 merges lines
                *(bf16x4*)&P_lds[w][r15][16 * t + 4 * g] = *(bf16x4*)pb;
            }
            // wave-private LDS bounce; compiler inserts the lgkmcnt wait
            const bf16x8 pa0 = *(const bf16x8*)&P_lds[w][r15][8 * g];
            const bf16x8 pa1 = *(const bf16x8*)&P_lds[w][r15][32 + 8 * g];
            #pragma unroll
            for (int t2 = 0; t2 < 4; ++t2) {
                const __bf16* vp = Vbase + (size_t)(16 * t2) * L_SEQ + k0;
                ctx[t2] = __builtin_amdgcn_mfma_f32_16x16x32_bf16(pa0, *(const bf16x8*)vp,        ctx[t2], 0, 0, 0);
                ctx[t2] = __builtin_amdgcn_mfma_f32_16x16x32_bf16(pa1, *(const bf16x8*)(vp + 32), ctx[t2], 0, 0, 0);
            }
            #pragma unroll
            for (int i = 0; i < 8; ++i) kf[i] = kn[i];
        }
    }

    // ctx store: D rows = q_local 4g+r, cols = 16t2 + r15
    const int qc = qt * 64 + w * 16 + 4 * g;
    #pragma unroll
    for (int t2 = 0; t2 < 4; ++t2) {
        #pragma unroll
        for (int r = 0; r < 4; ++r) {
            ctx_out[((size_t)bh * L_SEQ + qc + r) * D_HEAD + 16 * t2 + r15] = ctx[t2][r];
        }
    }
}

// ===================== fallback (round-1 verified kernel) =====================
__global__ __launch_bounds__(256) void sdpa_fallback(
    const float* __restrict__ Q, const float* __restrict__ K,
    const float* __restrict__ V, const float* __restrict__ scale_p,
    const int* __restrict__ mask, float* __restrict__ ctx_out,
    float* __restrict__ attn_out)
{
    __shared__ __bf16 K_lds[64][72];
    __shared__ __bf16 V_lds[64][72];
    __shared__ __bf16 P_lds[4][16][72];

    const int tid = threadIdx.x;
    const int w   = tid >> 6;
    const int l   = tid & 63;
    const int r15 = l & 15;
    const int g   = l >> 4;

    const int qt = blockIdx.x & 31;
    const int bh = blockIdx.x >> 5;
    const int b  = bh >> 4;
    const int q0 = qt * 64;

    const float scale = *scale_p;
    const float* Qp = Q + (size_t)bh * L_SEQ * D_HEAD;
    const float* Kp = K + (size_t)bh * L_SEQ * D_HEAD;
    const float* Vp = V + (size_t)bh * L_SEQ * D_HEAD;
    const int*   Mp = mask + (size_t)b * L_SEQ * L_SEQ;

    bf16x8 aq[2];
    {
        const float* qrow = Qp + (size_t)(q0 + w * 16 + r15) * D_HEAD;
        #pragma unroll
        for (int kk = 0; kk < 2; ++kk) {
            const float* s = qrow + kk * 32 + g * 8;
            bf16x8 v;
            #pragma unroll
            for (int j = 0; j < 8; ++j) v[j] = (__bf16)s[j];
            aq[kk] = v;
        }
    }

    const int srow = tid >> 2;
    const int scol = (tid & 3) * 16;
    const int qrow_base = q0 + w * 16 + g * 4;

    float lsum[4] = {0.f, 0.f, 0.f, 0.f};

    for (int ch = 0; ch < 32; ++ch) {
        const int k0 = ch * 64;
        __syncthreads();
        {
            const float4* s4 = (const float4*)(Kp + (size_t)(k0 + srow) * D_HEAD + scol);
            __bf16 tmp[16];
            #pragma unroll
            for (int i = 0; i < 4; ++i) {
                float4 f = s4[i];
                tmp[i*4+0] = (__bf16)f.x; tmp[i*4+1] = (__bf16)f.y;
                tmp[i*4+2] = (__bf16)f.z; tmp[i*4+3] = (__bf16)f.w;
            }
            *(bf16x8*)&K_lds[srow][scol]     = *(bf16x8*)&tmp[0];
            *(bf16x8*)&K_lds[srow][scol + 8] = *(bf16x8*)&tmp[8];
        }
        __syncthreads();

        f32x4 acc[4] = {{0,0,0,0},{0,0,0,0},{0,0,0,0},{0,0,0,0}};
        #pragma unroll
        for (int t = 0; t < 4; ++t) {
            #pragma unroll
            for (int kk = 0; kk < 2; ++kk) {
                bf16x8 bk = *(const bf16x8*)&K_lds[t * 16 + r15][kk * 32 + g * 8];
                acc[t] = __builtin_amdgcn_mfma_f32_16x16x32_bf16(aq[kk], bk, acc[t], 0, 0, 0);
            }
        }
        #pragma unroll
        for (int t = 0; t < 4; ++t) {
            const int kcol = k0 + t * 16 + r15;
            #pragma unroll
            for (int r = 0; r < 4; ++r) {
                const int mk = Mp[(size_t)(qrow_base + r) * L_SEQ + kcol];
                const float s = acc[t][r] * scale;
                const float e = mk ? 0.0f : __expf(s);
                lsum[r] += e;
            }
        }
    }

    #pragma unroll
    for (int r = 0; r < 4; ++r) {
        float v = lsum[r];
        v += __shfl_xor(v, 1);
        v += __shfl_xor(v, 2);
        v += __shfl_xor(v, 4);
        v += __shfl_xor(v, 8);
        lsum[r] = 1.0f / v;
    }

    f32x4 ctx[4] = {{0,0,0,0},{0,0,0,0},{0,0,0,0},{0,0,0,0}};
    for (int ch = 0; ch < 32; ++ch) {
        const int k0 = ch * 64;
        __syncthreads();
        {
            const float4* s4 = (const float4*)(Kp + (size_t)(k0 + srow) * D_HEAD + scol);
            __bf16 tmp[16];
            #pragma unroll
            for (int i = 0; i < 4; ++i) {
                float4 f = s4[i];
                tmp[i*4+0] = (__bf16)f.x; tmp[i*4+1] = (__bf16)f.y;
                tmp[i*4+2] = (__bf16)f.z; tmp[i*4+3] = (__bf16)f.w;
            }
            *(bf16x8*)&K_lds[srow][scol]     = *(bf16x8*)&tmp[0];
            *(bf16x8*)&K_lds[srow][scol + 8] = *(bf16x8*)&tmp[8];
        }
        {
            const float4* s4 = (const float4*)(Vp + (size_t)(k0 + srow) * D_HEAD + scol);
            #pragma unroll
            for (int i = 0; i < 4; ++i) {
                float4 f = s4[i];
                V_lds[scol + i*4 + 0][srow] = (__bf16)f.x;
                V_lds[scol + i*4 + 1][srow] = (__bf16)f.y;
                V_lds[scol + i*4 + 2][srow] = (__bf16)f.z;
                V_lds[scol + i*4 + 3][srow] = (__bf16)f.w;
            }
        }
        __syncthreads();

        f32x4 acc[4] = {{0,0,0,0},{0,0,0,0},{0,0,0,0},{0,0,0,0}};
        #pragma unroll
        for (int t = 0; t < 4; ++t) {
            #pragma unroll
            for (int kk = 0; kk < 2; ++kk) {
                bf16x8 bk = *(const bf16x8*)&K_lds[t * 16 + r15][kk * 32 + g * 8];
                acc[t] = __builtin_amdgcn_mfma_f32_16x16x32_bf16(aq[kk], bk, acc[t], 0, 0, 0);
            }
        }
        #pragma unroll
        for (int t = 0; t < 4; ++t) {
            const int kcol = k0 + t * 16 + r15;
            #pragma unroll
            for (int r = 0; r < 4; ++r) {
                const int mk = Mp[(size_t)(qrow_base + r) * L_SEQ + kcol];
                const float s = acc[t][r] * scale;
                const float p = mk ? 0.0f : __expf(s) * lsum[r];
                __builtin_nontemporal_store(
                    p, &attn_out[((size_t)bh * L_SEQ + qrow_base + r) * L_SEQ + kcol]);
                P_lds[w][g * 4 + r][t * 16 + r15] = (__bf16)p;
            }
        }
        #pragma unroll
        for (int t2 = 0; t2 < 4; ++t2) {
            #pragma unroll
            for (int kk = 0; kk < 2; ++kk) {
                bf16x8 pa = *(const bf16x8*)&P_lds[w][r15][kk * 32 + g * 8];
                bf16x8 pv = *(const bf16x8*)&V_lds[t2 * 16 + r15][kk * 32 + g * 8];
                ctx[t2] = __builtin_amdgcn_mfma_f32_16x16x32_bf16(pa, pv, ctx[t2], 0, 0, 0);
            }
        }
    }

    #pragma unroll
    for (int t2 = 0; t2 < 4; ++t2) {
        #pragma unroll
        for (int r = 0; r < 4; ++r) {
            __builtin_nontemporal_store(
                ctx[t2][r],
                &ctx_out[((size_t)bh * L_SEQ + qrow_base + r) * D_HEAD + t2 * 16 + r15]);
        }
    }
}

// ============================ launcher ============================
extern "C" void kernel_launch(void* const* d_in, const int* in_sizes, int n_in,
                              void* d_out, int out_size, void* d_ws, size_t ws_size,
                              hipStream_t stream) {
    const float* Q     = (const float*)d_in[0];
    const float* K     = (const float*)d_in[1];
    const float* V     = (const float*)d_in[2];
    const float* scale = (const float*)d_in[3];
    const int*   mask  = (const int*)d_in[4];

    float* ctx_out  = (float*)d_out;
    float* attn_out = (float*)d_out + (size_t)NBH * L_SEQ * D_HEAD;

    const size_t bfbytes = (size_t)NBH * L_SEQ * D_HEAD * 2;  // 8,388,608
    const size_t need = 3 * bfbytes + (size_t)2 * L_SEQ * (L_SEQ / 32) * 4; // +1MB mask bits

    if (ws_size >= need) {
        __bf16* Qb  = (__bf16*)d_ws;
        __bf16* Kb  = Qb + (size_t)NBH * L_SEQ * D_HEAD;
        __bf16* VbT = Kb + (size_t)NBH * L_SEQ * D_HEAD;
        unsigned int* mp = (unsigned int*)((char*)d_ws + 3 * bfbytes);

        hipLaunchKernelGGL(prep_qk,   dim3(4096),  dim3(256), 0, stream, Q, K, scale, Qb, Kb);
        hipLaunchKernelGGL(prep_vt,   dim3(1024),  dim3(256), 0, stream, V, VbT);
        hipLaunchKernelGGL(prep_mask, dim3(32768), dim3(256), 0, stream, mask, mp);
        hipLaunchKernelGGL(sdpa_main, dim3(1024),  dim3(256), 0, stream,
                           Qb, Kb, VbT, mp, ctx_out, attn_out);
    } else {
        hipLaunchKernelGGL(sdpa_fallback, dim3(1024), dim3(256), 0, stream,
                           Q, K, V, scale, mask, ctx_out, attn_out);
    }
}

// Round 5
// 200.067 us; speedup vs baseline: 2.2617x; 2.2617x over previous
//
#include <hip/hip_runtime.h>
#include <hip/hip_bf16.h>
#include <cstdint>

// Problem constants: B=2, H=16, L=2048, D=64
#define L_SEQ 2048
#define D_HEAD 64
#define N_HEADS 16
#define NBH 32   // B*H

typedef __attribute__((ext_vector_type(8))) __bf16 bf16x8;
typedef __attribute__((ext_vector_type(4))) __bf16 bf16x4;
typedef __attribute__((ext_vector_type(4))) float f32x4;

// ============================ prep kernels ============================

// Qb = bf16(Q * scale * log2e)  (so epilogue is exp2);  Kb = bf16(K)
__global__ __launch_bounds__(256) void prep_qk(const float* __restrict__ Q,
                                               const float* __restrict__ K,
                                               const float* __restrict__ scale_p,
                                               __bf16* __restrict__ Qb,
                                               __bf16* __restrict__ Kb) {
    const float c = scale_p[0] * 1.4426950408889634f;
    const size_t i = ((size_t)blockIdx.x * 256 + threadIdx.x) * 4;
    float4 q = *(const float4*)(Q + i);
    float4 k = *(const float4*)(K + i);
    __bf16 qo[4], ko[4];
    qo[0] = (__bf16)(q.x * c); qo[1] = (__bf16)(q.y * c);
    qo[2] = (__bf16)(q.z * c); qo[3] = (__bf16)(q.w * c);
    ko[0] = (__bf16)k.x; ko[1] = (__bf16)k.y; ko[2] = (__bf16)k.z; ko[3] = (__bf16)k.w;
    *(bf16x4*)(Qb + i) = *(bf16x4*)qo;
    *(bf16x4*)(Kb + i) = *(bf16x4*)ko;
}

// VbT[bh][d][k] = bf16(V[bh][k][d])  -- tiled transpose through LDS
__global__ __launch_bounds__(256) void prep_vt(const float* __restrict__ V,
                                               __bf16* __restrict__ VbT) {
    __shared__ __bf16 tile[64][72];
    const int bh = blockIdx.x >> 5;
    const int kt = blockIdx.x & 31;
    const int tid = threadIdx.x;
    const int r = tid >> 2;          // 0..63
    const int c = (tid & 3) * 16;    // 0,16,32,48
    const float* src = V + ((size_t)bh * L_SEQ + (size_t)kt * 64 + r) * D_HEAD + c;
    #pragma unroll
    for (int i = 0; i < 4; ++i) {
        float4 f = ((const float4*)src)[i];
        tile[r][c + i * 4 + 0] = (__bf16)f.x;
        tile[r][c + i * 4 + 1] = (__bf16)f.y;
        tile[r][c + i * 4 + 2] = (__bf16)f.z;
        tile[r][c + i * 4 + 3] = (__bf16)f.w;
    }
    __syncthreads();
    __bf16 out[16];
    #pragma unroll
    for (int j = 0; j < 16; ++j) out[j] = tile[c + j][r];   // [k][d] -> row d
    __bf16* dst = VbT + ((size_t)bh * D_HEAD + r) * L_SEQ + (size_t)kt * 64 + c;
    *(bf16x8*)dst       = *(bf16x8*)&out[0];
    *(bf16x8*)(dst + 8) = *(bf16x8*)&out[8];
}

// pack mask int32 -> bit per k: mp[row][kword], row in [B*L), 64 words/row
__global__ __launch_bounds__(256) void prep_mask(const int* __restrict__ mask,
                                                 unsigned int* __restrict__ mp) {
    const int wv   = blockIdx.x * 4 + (threadIdx.x >> 6);
    const int lane = threadIdx.x & 63;
    const int row  = wv >> 5;            // 0..4095
    const int k0   = (wv & 31) * 64;
    const int m = mask[(size_t)row * L_SEQ + k0 + lane];
    const unsigned long long b = __ballot(m != 0);
    if (lane < 2) mp[row * 64 + (k0 >> 5) + lane] = (unsigned int)(b >> (32 * lane));
}

// ============================ main kernel ============================
// R1 structure (barrier-synced LDS staging, proven fastest) with:
//  - bf16 pre-converted Q (scale*log2e folded), K, V^T -> staging is plain
//    16B copies, no cvt storm, no transpose scatter (bank conflicts gone)
//  - packed bitmask: 4 broadcast uint2 loads per chunk instead of 16 ints
//  - attn emitted from the bf16 P_lds tile via FULL-LINE nontemporal stores:
//    each instruction writes 4 rows x 256B contiguous (2 full 128B lines/row)
//    instead of 4 rows x 64B half-lines -> lifts the ~2 TB/s NT write cap.
__global__ __launch_bounds__(256) void sdpa_main(
    const __bf16* __restrict__ Qb, const __bf16* __restrict__ Kb,
    const __bf16* __restrict__ VbT, const unsigned int* __restrict__ mp,
    float* __restrict__ ctx_out, float* __restrict__ attn_out)
{
    __shared__ __bf16 K_lds[64][72];
    __shared__ __bf16 V_lds[64][72];   // [d][k_local]
    __shared__ __bf16 P_lds[4][16][72];

    const int tid = threadIdx.x;
    const int w   = tid >> 6;     // wave 0..3
    const int l   = tid & 63;     // lane
    const int r15 = l & 15;
    const int g   = l >> 4;

    const int qt = blockIdx.x & 31;
    const int bh = blockIdx.x >> 5;
    const int b  = bh >> 4;
    const int q0 = qt * 64;

    const __bf16* Kp = Kb  + (size_t)bh * L_SEQ * D_HEAD;
    const __bf16* Vp = VbT + (size_t)bh * D_HEAD * L_SEQ;

    // Q fragments (bf16, pre-scaled): lane holds A[row=r15][k=kk*32+8g+j]
    bf16x8 aq[2];
    {
        const __bf16* qrow = Qb + ((size_t)bh * L_SEQ + q0 + w * 16 + r15) * D_HEAD;
        aq[0] = *(const bf16x8*)(qrow + 8 * g);
        aq[1] = *(const bf16x8*)(qrow + 32 + 8 * g);
    }

    // staging decomposition: 64x64 bf16 tile, thread -> 16 consecutive bf16
    const int srow = tid >> 2;         // 0..63
    const int scol = (tid & 3) * 16;   // 0,16,32,48

    const int qrow_base = q0 + w * 16 + g * 4;           // + r gives C rows
    const int mrow_base = b * L_SEQ + qrow_base;         // packed mask rows

    float lsum[4] = {0.f, 0.f, 0.f, 0.f};

    // ================= Pass 1: row sums =================
    for (int ch = 0; ch < 32; ++ch) {
        const int k0 = ch * 64;
        __syncthreads();
        *(bf16x8*)&K_lds[srow][scol]     = *(const bf16x8*)(Kp + (size_t)(k0 + srow) * D_HEAD + scol);
        *(bf16x8*)&K_lds[srow][scol + 8] = *(const bf16x8*)(Kp + (size_t)(k0 + srow) * D_HEAD + scol + 8);
        __syncthreads();

        uint2 mw[4];
        #pragma unroll
        for (int r = 0; r < 4; ++r)
            mw[r] = *(const uint2*)(mp + (size_t)(mrow_base + r) * 64 + 2 * ch);

        f32x4 acc[4] = {{0,0,0,0},{0,0,0,0},{0,0,0,0},{0,0,0,0}};
        #pragma unroll
        for (int t = 0; t < 4; ++t) {
            #pragma unroll
            for (int kk = 0; kk < 2; ++kk) {
                bf16x8 bk = *(const bf16x8*)&K_lds[t * 16 + r15][kk * 32 + g * 8];
                acc[t] = __builtin_amdgcn_mfma_f32_16x16x32_bf16(aq[kk], bk, acc[t], 0, 0, 0);
            }
        }
        #pragma unroll
        for (int t = 0; t < 4; ++t) {
            const int sh = (t & 1) * 16 + r15;
            #pragma unroll
            for (int r = 0; r < 4; ++r) {
                const unsigned int word = (t & 2) ? mw[r].y : mw[r].x;
                const float e = __builtin_exp2f(acc[t][r]);
                lsum[r] += ((word >> sh) & 1u) ? 0.f : e;
            }
        }
    }

    #pragma unroll
    for (int r = 0; r < 4; ++r) {
        float v = lsum[r];
        v += __shfl_xor(v, 1);
        v += __shfl_xor(v, 2);
        v += __shfl_xor(v, 4);
        v += __shfl_xor(v, 8);
        lsum[r] = 1.0f / v;
    }

    // ================= Pass 2: PV + full-line attn stores =================
    f32x4 ctx[4] = {{0,0,0,0},{0,0,0,0},{0,0,0,0},{0,0,0,0}};

    // attn store coords: lane stores cols sc..sc+3 of rows (4i + sr)
    const int sr = l >> 4;          // 0..3
    const int sc = (l & 15) * 4;    // 0..60
    float* abase = attn_out + ((size_t)bh * L_SEQ + q0 + w * 16) * L_SEQ;

    for (int ch = 0; ch < 32; ++ch) {
        const int k0 = ch * 64;
        __syncthreads();
        *(bf16x8*)&K_lds[srow][scol]     = *(const bf16x8*)(Kp + (size_t)(k0 + srow) * D_HEAD + scol);
        *(bf16x8*)&K_lds[srow][scol + 8] = *(const bf16x8*)(Kp + (size_t)(k0 + srow) * D_HEAD + scol + 8);
        *(bf16x8*)&V_lds[srow][scol]     = *(const bf16x8*)(Vp + (size_t)srow * L_SEQ + k0 + scol);
        *(bf16x8*)&V_lds[srow][scol + 8] = *(const bf16x8*)(Vp + (size_t)srow * L_SEQ + k0 + scol + 8);
        __syncthreads();

        uint2 mw[4];
        #pragma unroll
        for (int r = 0; r < 4; ++r)
            mw[r] = *(const uint2*)(mp + (size_t)(mrow_base + r) * 64 + 2 * ch);

        f32x4 acc[4] = {{0,0,0,0},{0,0,0,0},{0,0,0,0},{0,0,0,0}};
        #pragma unroll
        for (int t = 0; t < 4; ++t) {
            #pragma unroll
            for (int kk = 0; kk < 2; ++kk) {
                bf16x8 bk = *(const bf16x8*)&K_lds[t * 16 + r15][kk * 32 + g * 8];
                acc[t] = __builtin_amdgcn_mfma_f32_16x16x32_bf16(aq[kk], bk, acc[t], 0, 0, 0);
            }
        }
        // epilogue: p = exp2(s)*inv (masked), stash bf16 P for PV + attn store
        #pragma unroll
        for (int t = 0; t < 4; ++t) {
            const int sh = (t & 1) * 16 + r15;
            #pragma unroll
            for (int r = 0; r < 4; ++r) {
                const unsigned int word = (t & 2) ? mw[r].y : mw[r].x;
                float e = __builtin_exp2f(acc[t][r]) * lsum[r];
                e = ((word >> sh) & 1u) ? 0.f : e;
                P_lds[w][g * 4 + r][t * 16 + r15] = (__bf16)e;
            }
        }
        // PV: P_lds[w] is wave-private; compiler inserts the lgkm wait.
        const bf16x8 pa0 = *(const bf16x8*)&P_lds[w][r15][8 * g];
        const bf16x8 pa1 = *(const bf16x8*)&P_lds[w][r15][32 + 8 * g];
        #pragma unroll
        for (int t2 = 0; t2 < 4; ++t2) {
            bf16x8 pv0 = *(const bf16x8*)&V_lds[t2 * 16 + r15][8 * g];
            bf16x8 pv1 = *(const bf16x8*)&V_lds[t2 * 16 + r15][32 + 8 * g];
            ctx[t2] = __builtin_amdgcn_mfma_f32_16x16x32_bf16(pa0, pv0, ctx[t2], 0, 0, 0);
            ctx[t2] = __builtin_amdgcn_mfma_f32_16x16x32_bf16(pa1, pv1, ctx[t2], 0, 0, 0);
        }
        // attn store from P_lds: per instr 4 rows x 256B contiguous (full lines)
        #pragma unroll
        for (int i = 0; i < 4; ++i) {
            const int row = 4 * i + sr;
            const uint2 raw = *(const uint2*)&P_lds[w][row][sc];
            f32x4 o;
            o[0] = __uint_as_float(raw.x << 16);
            o[1] = __uint_as_float(raw.x & 0xFFFF0000u);
            o[2] = __uint_as_float(raw.y << 16);
            o[3] = __uint_as_float(raw.y & 0xFFFF0000u);
            __builtin_nontemporal_store(o, (f32x4*)(abase + (size_t)row * L_SEQ + k0 + sc));
        }
    }

    // ctx store (16 MB total -- minor)
    #pragma unroll
    for (int t2 = 0; t2 < 4; ++t2) {
        #pragma unroll
        for (int r = 0; r < 4; ++r) {
            __builtin_nontemporal_store(
                ctx[t2][r],
                &ctx_out[((size_t)bh * L_SEQ + qrow_base + r) * D_HEAD + t2 * 16 + r15]);
        }
    }
}

// ===================== fallback (round-1 verified kernel) =====================
__global__ __launch_bounds__(256) void sdpa_fallback(
    const float* __restrict__ Q, const float* __restrict__ K,
    const float* __restrict__ V, const float* __restrict__ scale_p,
    const int* __restrict__ mask, float* __restrict__ ctx_out,
    float* __restrict__ attn_out)
{
    __shared__ __bf16 K_lds[64][72];
    __shared__ __bf16 V_lds[64][72];
    __shared__ __bf16 P_lds[4][16][72];

    const int tid = threadIdx.x;
    const int w   = tid >> 6;
    const int l   = tid & 63;
    const int r15 = l & 15;
    const int g   = l >> 4;

    const int qt = blockIdx.x & 31;
    const int bh = blockIdx.x >> 5;
    const int b  = bh >> 4;
    const int q0 = qt * 64;

    const float scale = *scale_p;
    const float* Qp = Q + (size_t)bh * L_SEQ * D_HEAD;
    const float* Kp = K + (size_t)bh * L_SEQ * D_HEAD;
    const float* Vp = V + (size_t)bh * L_SEQ * D_HEAD;
    const int*   Mp = mask + (size_t)b * L_SEQ * L_SEQ;

    bf16x8 aq[2];
    {
        const float* qrow = Qp + (size_t)(q0 + w * 16 + r15) * D_HEAD;
        #pragma unroll
        for (int kk = 0; kk < 2; ++kk) {
            const float* s = qrow + kk * 32 + g * 8;
            bf16x8 v;
            #pragma unroll
            for (int j = 0; j < 8; ++j) v[j] = (__bf16)s[j];
            aq[kk] = v;
        }
    }

    const int srow = tid >> 2;
    const int scol = (tid & 3) * 16;
    const int qrow_base = q0 + w * 16 + g * 4;

    float lsum[4] = {0.f, 0.f, 0.f, 0.f};

    for (int ch = 0; ch < 32; ++ch) {
        const int k0 = ch * 64;
        __syncthreads();
        {
            const float4* s4 = (const float4*)(Kp + (size_t)(k0 + srow) * D_HEAD + scol);
            __bf16 tmp[16];
            #pragma unroll
            for (int i = 0; i < 4; ++i) {
                float4 f = s4[i];
                tmp[i*4+0] = (__bf16)f.x; tmp[i*4+1] = (__bf16)f.y;
                tmp[i*4+2] = (__bf16)f.z; tmp[i*4+3] = (__bf16)f.w;
            }
            *(bf16x8*)&K_lds[srow][scol]     = *(bf16x8*)&tmp[0];
            *(bf16x8*)&K_lds[srow][scol + 8] = *(bf16x8*)&tmp[8];
        }
        __syncthreads();

        f32x4 acc[4] = {{0,0,0,0},{0,0,0,0},{0,0,0,0},{0,0,0,0}};
        #pragma unroll
        for (int t = 0; t < 4; ++t) {
            #pragma unroll
            for (int kk = 0; kk < 2; ++kk) {
                bf16x8 bk = *(const bf16x8*)&K_lds[t * 16 + r15][kk * 32 + g * 8];
                acc[t] = __builtin_amdgcn_mfma_f32_16x16x32_bf16(aq[kk], bk, acc[t], 0, 0, 0);
            }
        }
        #pragma unroll
        for (int t = 0; t < 4; ++t) {
            const int kcol = k0 + t * 16 + r15;
            #pragma unroll
            for (int r = 0; r < 4; ++r) {
                const int mk = Mp[(size_t)(qrow_base + r) * L_SEQ + kcol];
                const float s = acc[t][r] * scale;
                const float e = mk ? 0.0f : __expf(s);
                lsum[r] += e;
            }
        }
    }

    #pragma unroll
    for (int r = 0; r < 4; ++r) {
        float v = lsum[r];
        v += __shfl_xor(v, 1);
        v += __shfl_xor(v, 2);
        v += __shfl_xor(v, 4);
        v += __shfl_xor(v, 8);
        lsum[r] = 1.0f / v;
    }

    f32x4 ctx[4] = {{0,0,0,0},{0,0,0,0},{0,0,0,0},{0,0,0,0}};
    for (int ch = 0; ch < 32; ++ch) {
        const int k0 = ch * 64;
        __syncthreads();
        {
            const float4* s4 = (const float4*)(Kp + (size_t)(k0 + srow) * D_HEAD + scol);
            __bf16 tmp[16];
            #pragma unroll
            for (int i = 0; i < 4; ++i) {
                float4 f = s4[i];
                tmp[i*4+0] = (__bf16)f.x; tmp[i*4+1] = (__bf16)f.y;
                tmp[i*4+2] = (__bf16)f.z; tmp[i*4+3] = (__bf16)f.w;
            }
            *(bf16x8*)&K_lds[srow][scol]     = *(bf16x8*)&tmp[0];
            *(bf16x8*)&K_lds[srow][scol + 8] = *(bf16x8*)&tmp[8];
        }
        {
            const float4* s4 = (const float4*)(Vp + (size_t)(k0 + srow) * D_HEAD + scol);
            #pragma unroll
            for (int i = 0; i < 4; ++i) {
                float4 f = s4[i];
                V_lds[scol + i*4 + 0][srow] = (__bf16)f.x;
                V_lds[scol + i*4 + 1][srow] = (__bf16)f.y;
                V_lds[scol + i*4 + 2][srow] = (__bf16)f.z;
                V_lds[scol + i*4 + 3][srow] = (__bf16)f.w;
            }
        }
        __syncthreads();

        f32x4 acc[4] = {{0,0,0,0},{0,0,0,0},{0,0,0,0},{0,0,0,0}};
        #pragma unroll
        for (int t = 0; t < 4; ++t) {
            #pragma unroll
            for (int kk = 0; kk < 2; ++kk) {
                bf16x8 bk = *(const bf16x8*)&K_lds[t * 16 + r15][kk * 32 + g * 8];
                acc[t] = __builtin_amdgcn_mfma_f32_16x16x32_bf16(aq[kk], bk, acc[t], 0, 0, 0);
            }
        }
        #pragma unroll
        for (int t = 0; t < 4; ++t) {
            const int kcol = k0 + t * 16 + r15;
            #pragma unroll
            for (int r = 0; r < 4; ++r) {
                const int mk = Mp[(size_t)(qrow_base + r) * L_SEQ + kcol];
                const float s = acc[t][r] * scale;
                const float p = mk ? 0.0f : __expf(s) * lsum[r];
                __builtin_nontemporal_store(
                    p, &attn_out[((size_t)bh * L_SEQ + qrow_base + r) * L_SEQ + kcol]);
                P_lds[w][g * 4 + r][t * 16 + r15] = (__bf16)p;
            }
        }
        #pragma unroll
        for (int t2 = 0; t2 < 4; ++t2) {
            #pragma unroll
            for (int kk = 0; kk < 2; ++kk) {
                bf16x8 pa = *(const bf16x8*)&P_lds[w][r15][kk * 32 + g * 8];
                bf16x8 pv = *(const bf16x8*)&V_lds[t2 * 16 + r15][kk * 32 + g * 8];
                ctx[t2] = __builtin_amdgcn_mfma_f32_16x16x32_bf16(pa, pv, ctx[t2], 0, 0, 0);
            }
        }
    }

    #pragma unroll
    for (int t2 = 0; t2 < 4; ++t2) {
        #pragma unroll
        for (int r = 0; r < 4; ++r) {
            __builtin_nontemporal_store(
                ctx[t2][r],
                &ctx_out[((size_t)bh * L_SEQ + qrow_base + r) * D_HEAD + t2 * 16 + r15]);
        }
    }
}

// ============================ launcher ============================
extern "C" void kernel_launch(void* const* d_in, const int* in_sizes, int n_in,
                              void* d_out, int out_size, void* d_ws, size_t ws_size,
                              hipStream_t stream) {
    const float* Q     = (const float*)d_in[0];
    const float* K     = (const float*)d_in[1];
    const float* V     = (const float*)d_in[2];
    const float* scale = (const float*)d_in[3];
    const int*   mask  = (const int*)d_in[4];

    float* ctx_out  = (float*)d_out;
    float* attn_out = (float*)d_out + (size_t)NBH * L_SEQ * D_HEAD;

    const size_t bfbytes = (size_t)NBH * L_SEQ * D_HEAD * 2;  // 8,388,608
    const size_t need = 3 * bfbytes + (size_t)2 * L_SEQ * (L_SEQ / 32) * 4; // +1MB mask bits

    if (ws_size >= need) {
        __bf16* Qb  = (__bf16*)d_ws;
        __bf16* Kb  = Qb + (size_t)NBH * L_SEQ * D_HEAD;
        __bf16* VbT = Kb + (size_t)NBH * L_SEQ * D_HEAD;
        unsigned int* mp = (unsigned int*)((char*)d_ws + 3 * bfbytes);

        hipLaunchKernelGGL(prep_qk,   dim3(4096),  dim3(256), 0, stream, Q, K, scale, Qb, Kb);
        hipLaunchKernelGGL(prep_vt,   dim3(1024),  dim3(256), 0, stream, V, VbT);
        hipLaunchKernelGGL(prep_mask, dim3(32768), dim3(256), 0, stream, mask, mp);
        hipLaunchKernelGGL(sdpa_main, dim3(1024),  dim3(256), 0, stream,
                           Qb, Kb, VbT, mp, ctx_out, attn_out);
    } else {
        hipLaunchKernelGGL(sdpa_fallback, dim3(1024), dim3(256), 0, stream,
                           Q, K, V, scale, mask, ctx_out, attn_out);
    }
}